// Round 12
// baseline (943.872 us; speedup 1.0000x reference)
//
#include <hip/hip_runtime.h>
#include <hip/hip_bf16.h>
#include <math.h>

#define T_TOK 8192
#define M_DIM 2048
#define F_DIM 8192
#define E_NUM 8
#define CAP   1024

typedef unsigned short u16;
typedef __attribute__((ext_vector_type(8))) short short8;
typedef __attribute__((ext_vector_type(4))) float f32x4;

__device__ __forceinline__ u16 f2bf(float f){
  unsigned int x = __builtin_bit_cast(unsigned int, f);
  unsigned int lsb = (x >> 16) & 1u;
  x += 0x7fffu + lsb;
  return (u16)(x >> 16);
}
__device__ __forceinline__ unsigned int pack2(float a, float b){
  return (unsigned int)f2bf(a) | ((unsigned int)f2bf(b) << 16);
}

typedef __attribute__((address_space(3))) unsigned int lds_uint;
typedef __attribute__((address_space(1))) const unsigned int g_uint;
__device__ __forceinline__ void gl_lds16(const u16* g, u16* l){
  __builtin_amdgcn_global_load_lds((g_uint*)g, (lds_uint*)l, 16, 0, 0);
}
typedef __attribute__((address_space(3))) u16 lds_u16;
__device__ __forceinline__ unsigned int lds_off(u16* p){
  return (unsigned int)(unsigned long long)(lds_u16*)p;
}

__device__ __forceinline__ float gelu_tanh(float v){
  float u = 0.7978845608028654f * (v + 0.044715f * v * v * v);
  return 0.5f * v * (1.0f + tanhf(u));
}

// 256-row tiled layout (A-side: Xe, h): region = [256 n][32 k] u16 (16KB).
__device__ __forceinline__ size_t tiled256(int e, int n, int k, int nt256, int nkt){
  return ((((size_t)e * nt256 + (n >> 8)) * nkt + (k >> 6)) * 2 + ((k >> 5) & 1)) * 8192
         + (size_t)((n & 255) * 32 + ((((k >> 3) & 3) ^ ((n >> 1) & 3)) << 3) + (k & 7));
}
// 128-row tiled layout (B-side: w1T, w2T): region = [128 n][32 k] u16 (8KB).
__device__ __forceinline__ size_t tiled128(int e, int n, int k, int nt128, int nkt){
  return ((((size_t)e * nt128 + (n >> 7)) * nkt + (k >> 6)) * 2 + ((k >> 5) & 1)) * 4096
         + (size_t)((n & 127) * 32 + ((((k >> 3) & 3) ^ ((n >> 1) & 3)) << 3) + (k & 7));
}

// ---------------- gating: logits, softmax, argmax ----------------
__global__ __launch_bounds__(256) void gating_kernel(
    const float* __restrict__ x, const float* __restrict__ wg,
    int* __restrict__ expert_id, float* __restrict__ gate_val,
    float* __restrict__ mepart)
{
  int wave = threadIdx.x >> 6, lane = threadIdx.x & 63;
  int t = blockIdx.x * 4 + wave;
  float acc[8];
  #pragma unroll
  for (int e = 0; e < 8; ++e) acc[e] = 0.f;
  const float* xr = x + (size_t)t * M_DIM;
  for (int i = lane; i < M_DIM; i += 64) {
    float xv = xr[i];
    const float4* wr = (const float4*)(wg + (size_t)i * 8);
    float4 w0 = wr[0], w1v = wr[1];
    acc[0] += xv * w0.x;  acc[1] += xv * w0.y;  acc[2] += xv * w0.z;  acc[3] += xv * w0.w;
    acc[4] += xv * w1v.x; acc[5] += xv * w1v.y; acc[6] += xv * w1v.z; acc[7] += xv * w1v.w;
  }
  #pragma unroll
  for (int off = 32; off; off >>= 1)
    #pragma unroll
    for (int e = 0; e < 8; ++e) acc[e] += __shfl_xor(acc[e], off);

  float mx = acc[0]; int bi = 0;
  #pragma unroll
  for (int e = 1; e < 8; ++e) if (acc[e] > mx) { mx = acc[e]; bi = e; }
  float p[8]; float s = 0.f;
  #pragma unroll
  for (int e = 0; e < 8; ++e) { p[e] = expf(acc[e] - mx); s += p[e]; }
  float inv = 1.f / s;

  __shared__ float pl[4][8];
  if (lane == 0) {
    expert_id[t] = bi;
    gate_val[t] = p[bi] * inv;
    #pragma unroll
    for (int e = 0; e < 8; ++e) pl[wave][e] = p[e] * inv;
  }
  __syncthreads();
  if (threadIdx.x < 8) {
    float m = pl[0][threadIdx.x] + pl[1][threadIdx.x] + pl[2][threadIdx.x] + pl[3][threadIdx.x];
    mepart[blockIdx.x * 8 + threadIdx.x] = m;
  }
}

// ---------------- order-preserving scan (cumsum semantics) ----------------
__global__ __launch_bounds__(1024) void scan_kernel(
    const int* __restrict__ expert_id, const float* __restrict__ gate_val,
    const float* __restrict__ mepart, int nmep,
    int* __restrict__ slot_token, float* __restrict__ slot_gate,
    float* __restrict__ laux_out)
{
  __shared__ int wcnt[16][8];
  __shared__ int base[8];
  __shared__ float red[128][8];
  int tid = threadIdx.x, wave = tid >> 6, lane = tid & 63;
  if (tid < 8) base[tid] = 0;

  int e0 = tid & 7, g = tid >> 3;   // g in 0..127
  float mesum = 0.f;
  for (int r = g; r < nmep; r += 128) mesum += mepart[r * 8 + e0];
  red[g][e0] = mesum;
  __syncthreads();

  for (int tile = 0; tile < T_TOK / 1024; ++tile) {
    int t = tile * 1024 + tid;
    int e = expert_id[t];
    int lp = 0;
    #pragma unroll
    for (int ee = 0; ee < 8; ++ee) {
      unsigned long long m = __ballot(e == ee);
      if (lane == 0) wcnt[wave][ee] = __popcll(m);
      if (ee == e)   lp = __popcll(m & ((1ull << lane) - 1ull));
    }
    __syncthreads();
    int wp = 0;
    for (int w2 = 0; w2 < wave; ++w2) wp += wcnt[w2][e];
    int pos = base[e] + wp + lp;
    if (pos < CAP) {
      slot_token[e * CAP + pos] = t;
      slot_gate[e * CAP + pos] = gate_val[t];
    }
    __syncthreads();
    if (tid < 8) {
      int s = 0;
      for (int w2 = 0; w2 < 16; ++w2) s += wcnt[w2][tid];
      base[tid] += s;
    }
    __syncthreads();
  }

  if (tid < 8) {
    float me = 0.f;
    for (int r = 0; r < 128; ++r) me += red[r][tid];
    me /= (float)T_TOK;
    float ce = (float)base[tid] / (float)T_TOK;
    red[0][tid] = me * ce;
  }
  __syncthreads();
  if (tid == 0) {
    float s = 0.f;
    for (int e = 0; e < 8; ++e) s += red[0][e];
    *laux_out = s * (float)E_NUM;
  }
}

// -------- transpose + f32->bf16 + pack into 128-row tiled layout --------
__global__ __launch_bounds__(256) void transpose_cvt_kernel(
    const float* __restrict__ in, u16* __restrict__ out, int R, int Cc)
{
  __shared__ float tile[64][65];
  int e = blockIdx.z;
  const float* ine = in + (size_t)e * R * Cc;
  int r0 = blockIdx.y * 64, c0 = blockIdx.x * 64;
  int tr = threadIdx.x >> 4, tc = threadIdx.x & 15;
  #pragma unroll
  for (int it = 0; it < 4; ++it) {
    float4 v = *(const float4*)&ine[(size_t)(r0 + it * 16 + tr) * Cc + c0 + tc * 4];
    tile[it * 16 + tr][tc * 4 + 0] = v.x;
    tile[it * 16 + tr][tc * 4 + 1] = v.y;
    tile[it * 16 + tr][tc * 4 + 2] = v.z;
    tile[it * 16 + tr][tc * 4 + 3] = v.w;
  }
  __syncthreads();
  int nt128 = Cc >> 7, nkt = R >> 6;
  int oc = threadIdx.x >> 2, q = threadIdx.x & 3;
  int n = c0 + oc, k0 = r0 + q * 16;
  u16 vals[16];
  #pragma unroll
  for (int i = 0; i < 16; ++i) vals[i] = f2bf(tile[q * 16 + i][oc]);
  unsigned int w[8];
  #pragma unroll
  for (int i = 0; i < 8; ++i) w[i] = (unsigned int)vals[2 * i] | ((unsigned int)vals[2 * i + 1] << 16);
  uint4 pa; pa.x = w[0]; pa.y = w[1]; pa.z = w[2]; pa.w = w[3];
  uint4 pb; pb.x = w[4]; pb.y = w[5]; pb.z = w[6]; pb.w = w[7];
  *(uint4*)&out[tiled128(e, n, k0,     nt128, nkt)] = pa;
  *(uint4*)&out[tiled128(e, n, k0 + 8, nt128, nkt)] = pb;
}

// ------- dispatch: gather tokens -> Xe tiled256 bf16 -------
__global__ __launch_bounds__(256) void dispatch_kernel(
    const float* __restrict__ x, const int* __restrict__ slot_token,
    u16* __restrict__ Xe)
{
  int slot = blockIdx.x;
  int e = slot >> 10, c = slot & (CAP - 1);
  int t = slot_token[slot];
  int m = threadIdx.x * 8;
  uint4 pk;
  if (t < 0) {
    pk.x = pk.y = pk.z = pk.w = 0u;
  } else {
    const float* xr = x + (size_t)t * M_DIM + m;
    float4 a = *(const float4*)xr;
    float4 b = *(const float4*)(xr + 4);
    pk.x = pack2(a.x, a.y); pk.y = pack2(a.z, a.w);
    pk.z = pack2(b.x, b.y); pk.w = pack2(b.z, b.w);
  }
  *(uint4*)&Xe[tiled256(e, c, m, CAP >> 8, M_DIM >> 6)] = pk;
}

// ==== 256Mx128N BK=32 MFMA GEMM, SA[3]/SB[2] (64KB LDS), 2 blocks/CU ====
// 8 waves (4m x 2n), wave tile 64x64, acc[4][4]. Per k-tile (2 phases):
//  P1: read bfr(4)+af(2) from SA[t%3]/SB[t%2]; stage B[t+1]->SB[(t+1)%2]
//      (1 instr) THEN A[t+2]->SA[(t+2)%3] (2 instr); barrier; lgkmcnt(0);
//      8 MFMA (m-half 0); barrier.
//  P2: read af(2) (m-half 1); barrier; lgkmcnt(0); 8 MFMA; vmcnt(2)
//      (proves A[t+1],B[t+1]; leaves A[t+2] in flight); barrier.
// Two independent blocks per CU give 2 barrier groups -> ~2x staged delivery.
template<int EPI>
__global__ __launch_bounds__(512, 4) void gemmk(
    const u16* __restrict__ A,   // tiled256 [E][CAP/256][K/32 regions]
    const u16* __restrict__ B,   // tiled128 [E][NR/128][K/32 regions]
    const float* __restrict__ bias, // [E][NR]
    u16* __restrict__ Hout,      // EPI0: tiled256 h
    float* __restrict__ Out,     // EPI1: [T][M]
    const int* __restrict__ slot_token, const float* __restrict__ slot_gate,
    int K, int NR)
{
  __shared__ __align__(16) u16 SA[3][8192];  // 48KB
  __shared__ __align__(16) u16 SB[2][4096];  // 16KB

  int e = blockIdx.z;
  int n0 = blockIdx.x * 128, m0 = blockIdx.y * 256;
  int nkt = K >> 6;
  const u16* Atb = A + (((size_t)(e * (CAP >> 8) + (m0 >> 8)) * nkt) * 2) * 8192;
  const u16* Btb = B + (((size_t)(e * (NR >> 7) + (n0 >> 7)) * nkt) * 2) * 4096;

  int tid = threadIdx.x, wave = tid >> 6, lane = tid & 63;
  int wr = wave >> 1, wc = wave & 1;
  int l15 = lane & 15, g2 = lane >> 4;

  int rs = (l15 >> 1) & 3;
  int cg = (g2 ^ rs) * 8;
  int arow_base = (wr * 64 + l15) * 32 + cg;
  int brow_base = (wc * 64 + l15) * 32 + cg;

  unsigned aAddr[3], bAddr[2];
  #pragma unroll
  for (int b = 0; b < 3; ++b) aAddr[b] = lds_off(&SA[b][0]) + (unsigned)(arow_base * 2);
  #pragma unroll
  for (int b = 0; b < 2; ++b) bAddr[b] = lds_off(&SB[b][0]) + (unsigned)(brow_base * 2);

  f32x4 acc[4][4];
  #pragma unroll
  for (int m = 0; m < 4; ++m)
    #pragma unroll
    for (int n = 0; n < 4; ++n)
      acc[m][n] = (f32x4){0.f, 0.f, 0.f, 0.f};
  short8 bfr[4];

  auto stageA = [&](u16* region, int reg) {
    const u16* src = Atb + ((size_t)reg << 13);
    #pragma unroll
    for (int j = 0; j < 2; ++j)
      gl_lds16(src + (size_t)(j * 512 + tid) * 8, region + (j * 512 + (wave << 6)) * 8);
  };
  auto stageB = [&](u16* region, int reg) {
    const u16* src = Btb + ((size_t)reg << 12);
    gl_lds16(src + (size_t)tid * 8, region + (size_t)(wave << 6) * 8);
  };

  int nk = K >> 5;   // 32-k regions
  // prologue: B0, A0, A1 (5 instrs); vmcnt(2) proves B0,A0, leaves A1 in flight.
  stageB(&SB[0][0], 0);
  stageA(&SA[0][0], 0);
  stageA(&SA[1][0], 1);
  asm volatile("s_waitcnt vmcnt(2)");
  __builtin_amdgcn_sched_barrier(0);
  __builtin_amdgcn_s_barrier();

  int ia = 0, ib = 0;
  #pragma unroll 1
  for (int t = 0; t < nk; ++t) {
    int ia2 = ia + 2 >= 3 ? ia - 1 : ia + 2;
    int ib1 = ib ^ 1;
    int rb = t + 1 < nk ? t + 1 : nk - 1;   // clamped -> dead slot
    int ra = t + 2 < nk ? t + 2 : nk - 1;
    short8 af[2];
    // ---- P1: m-half 0 ----
    asm volatile("ds_read_b128 %0, %1 offset:0"    : "=v"(bfr[0]) : "v"(bAddr[ib]));
    asm volatile("ds_read_b128 %0, %1 offset:1024" : "=v"(bfr[1]) : "v"(bAddr[ib]));
    asm volatile("ds_read_b128 %0, %1 offset:2048" : "=v"(bfr[2]) : "v"(bAddr[ib]));
    asm volatile("ds_read_b128 %0, %1 offset:3072" : "=v"(bfr[3]) : "v"(bAddr[ib]));
    asm volatile("ds_read_b128 %0, %1 offset:0"    : "=v"(af[0]) : "v"(aAddr[ia]));
    asm volatile("ds_read_b128 %0, %1 offset:1024" : "=v"(af[1]) : "v"(aAddr[ia]));
    stageB(&SB[ib1][0], rb);          // B first (ledger: A[t+2] must be last)
    stageA(&SA[ia2][0], ra);
    __builtin_amdgcn_s_barrier();
    asm volatile("s_waitcnt lgkmcnt(0)");
    __builtin_amdgcn_sched_barrier(0);
    __builtin_amdgcn_s_setprio(1);
    #pragma unroll
    for (int m2 = 0; m2 < 2; ++m2)
      #pragma unroll
      for (int n2 = 0; n2 < 4; ++n2)
        acc[m2][n2] = __builtin_amdgcn_mfma_f32_16x16x32_bf16(
            af[m2], bfr[n2], acc[m2][n2], 0, 0, 0);
    __builtin_amdgcn_s_setprio(0);
    __builtin_amdgcn_s_barrier();
    // ---- P2: m-half 1 ----
    asm volatile("ds_read_b128 %0, %1 offset:2048" : "=v"(af[0]) : "v"(aAddr[ia]));
    asm volatile("ds_read_b128 %0, %1 offset:3072" : "=v"(af[1]) : "v"(aAddr[ia]));
    __builtin_amdgcn_s_barrier();
    asm volatile("s_waitcnt lgkmcnt(0)");
    __builtin_amdgcn_sched_barrier(0);
    __builtin_amdgcn_s_setprio(1);
    #pragma unroll
    for (int m2 = 0; m2 < 2; ++m2)
      #pragma unroll
      for (int n2 = 0; n2 < 4; ++n2)
        acc[2 + m2][n2] = __builtin_amdgcn_mfma_f32_16x16x32_bf16(
            af[m2], bfr[n2], acc[2 + m2][n2], 0, 0, 0);
    __builtin_amdgcn_s_setprio(0);
    asm volatile("s_waitcnt vmcnt(2)");
    __builtin_amdgcn_sched_barrier(0);
    __builtin_amdgcn_s_barrier();
    ia = ia + 1 >= 3 ? 0 : ia + 1;
    ib = ib1;
  }

  int wrb = wr * 64, wcb = wc * 64;
  const float* be = bias + (size_t)e * NR + n0;
  if (EPI == 0) {
    #pragma unroll
    for (int wm = 0; wm < 4; ++wm) {
      #pragma unroll
      for (int j = 0; j < 4; ++j) {
        int r = wrb + wm * 16 + g2 * 4 + j;
        #pragma unroll
        for (int n = 0; n < 4; ++n) {
          int c = wcb + n * 16 + l15;
          float v = acc[wm][n][j] + be[c];
          Hout[tiled256(e, m0 + r, n0 + c, CAP >> 8, F_DIM >> 6)] = f2bf(gelu_tanh(v));
        }
      }
    }
  } else {
    #pragma unroll
    for (int wm = 0; wm < 4; ++wm) {
      #pragma unroll
      for (int j = 0; j < 4; ++j) {
        int r = wrb + wm * 16 + g2 * 4 + j;
        int slot = e * CAP + m0 + r;
        int tk = slot_token[slot];
        if (tk >= 0) {
          float gv = slot_gate[slot];
          size_t rowoff = (size_t)tk * M_DIM + n0;
          #pragma unroll
          for (int n = 0; n < 4; ++n) {
            int c = wcb + n * 16 + l15;
            Out[rowoff + c] = gv * (acc[wm][n][j] + be[c]);
          }
        }
      }
    }
  }
}

extern "C" void kernel_launch(void* const* d_in, const int* in_sizes, int n_in,
                              void* d_out, int out_size, void* d_ws, size_t ws_size,
                              hipStream_t stream) {
  const float* x  = (const float*)d_in[0];
  const float* wg = (const float*)d_in[1];
  const float* w1 = (const float*)d_in[2];
  const float* b1 = (const float*)d_in[3];
  const float* w2 = (const float*)d_in[4];
  const float* b2 = (const float*)d_in[5];
  float* out = (float*)d_out;

  char* ws = (char*)d_ws;
  size_t o = 0;
  auto alloc = [&](size_t bytes) -> void* {
    void* p = ws + o;
    o += (bytes + 255) & ~(size_t)255;
    return p;
  };
  u16*   w1T        = (u16*)  alloc((size_t)E_NUM * F_DIM * M_DIM * 2);  // 256 MB
  u16*   w2T        = (u16*)  alloc((size_t)E_NUM * M_DIM * F_DIM * 2);  // 256 MB
  u16*   h          = (u16*)  alloc((size_t)E_NUM * CAP * F_DIM * 2);    // 128 MB
  u16*   Xe         = (u16*)  alloc((size_t)E_NUM * CAP * M_DIM * 2);    // 32 MB
  int*   expert_id  = (int*)  alloc(T_TOK * 4);
  float* gate_val   = (float*)alloc(T_TOK * 4);
  int*   slot_token = (int*)  alloc(E_NUM * CAP * 4);
  float* slot_gate  = (float*)alloc(E_NUM * CAP * 4);
  float* mepart     = (float*)alloc(2048 * 8 * 4);

  hipMemsetAsync(d_out, 0, (size_t)out_size * 4, stream);
  hipMemsetAsync(slot_token, 0xFF, E_NUM * CAP * 4, stream);

  gating_kernel<<<T_TOK / 4, 256, 0, stream>>>(x, wg, expert_id, gate_val, mepart);
  scan_kernel<<<1, 1024, 0, stream>>>(expert_id, gate_val, mepart, 2048,
                                      slot_token, slot_gate, out + (out_size - 1));
  transpose_cvt_kernel<<<dim3(128, 32, 8), 256, 0, stream>>>(w1, w1T, 2048, 8192);
  transpose_cvt_kernel<<<dim3(32, 128, 8), 256, 0, stream>>>(w2, w2T, 8192, 2048);
  dispatch_kernel<<<E_NUM * CAP, 256, 0, stream>>>(x, slot_token, Xe);

  gemmk<0><<<dim3(F_DIM / 128, CAP / 256, E_NUM), 512, 0, stream>>>(
      Xe, w1T, b1, h, nullptr, nullptr, nullptr, M_DIM, F_DIM);
  gemmk<1><<<dim3(M_DIM / 128, CAP / 256, E_NUM), 512, 0, stream>>>(
      h, w2T, b2, nullptr, out, slot_token, slot_gate, F_DIM, M_DIM);
}

// Round 13
// 904.005 us; speedup vs baseline: 1.0441x; 1.0441x over previous
//
#include <hip/hip_runtime.h>
#include <hip/hip_bf16.h>
#include <math.h>

#define T_TOK 8192
#define M_DIM 2048
#define F_DIM 8192
#define E_NUM 8
#define CAP   1024

typedef unsigned short u16;
typedef __attribute__((ext_vector_type(8))) short short8;
typedef __attribute__((ext_vector_type(4))) float f32x4;

__device__ __forceinline__ u16 f2bf(float f){
  unsigned int x = __builtin_bit_cast(unsigned int, f);
  unsigned int lsb = (x >> 16) & 1u;
  x += 0x7fffu + lsb;
  return (u16)(x >> 16);
}
__device__ __forceinline__ unsigned int pack2(float a, float b){
  return (unsigned int)f2bf(a) | ((unsigned int)f2bf(b) << 16);
}

typedef __attribute__((address_space(3))) unsigned int lds_uint;
typedef __attribute__((address_space(1))) const unsigned int g_uint;
__device__ __forceinline__ void gl_lds16(const u16* g, u16* l){
  __builtin_amdgcn_global_load_lds((g_uint*)g, (lds_uint*)l, 16, 0, 0);
}
typedef __attribute__((address_space(3))) u16 lds_u16;
__device__ __forceinline__ unsigned int lds_off(u16* p){
  return (unsigned int)(unsigned long long)(lds_u16*)p;
}

__device__ __forceinline__ float gelu_tanh(float v){
  float u = 0.7978845608028654f * (v + 0.044715f * v * v * v);
  return 0.5f * v * (1.0f + tanhf(u));
}

// Tiled+swizzled operand layout: half-tile = [256 rows n][32 cols k] u16,
// row r is 4 granules of 8; logical granule p stored at position p ^ ((r>>1)&3).
// Dims: [e][n/256][k/64][khalf][8192 u16]. nt256 = N/256, nkt = K/64.
__device__ __forceinline__ size_t tiled_off(int e, int n, int k, int nt256, int nkt){
  return ((((size_t)e * nt256 + (n >> 8)) * nkt + (k >> 6)) * 2 + ((k >> 5) & 1)) * 8192
         + (size_t)((n & 255) * 32 + ((((k >> 3) & 3) ^ ((n >> 1) & 3)) << 3) + (k & 7));
}

// ---------------- gating: logits, softmax, argmax ----------------
__global__ __launch_bounds__(256) void gating_kernel(
    const float* __restrict__ x, const float* __restrict__ wg,
    int* __restrict__ expert_id, float* __restrict__ gate_val,
    float* __restrict__ mepart)
{
  int wave = threadIdx.x >> 6, lane = threadIdx.x & 63;
  int t = blockIdx.x * 4 + wave;
  float acc[8];
  #pragma unroll
  for (int e = 0; e < 8; ++e) acc[e] = 0.f;
  const float* xr = x + (size_t)t * M_DIM;
  for (int i = lane; i < M_DIM; i += 64) {
    float xv = xr[i];
    const float4* wr = (const float4*)(wg + (size_t)i * 8);
    float4 w0 = wr[0], w1v = wr[1];
    acc[0] += xv * w0.x;  acc[1] += xv * w0.y;  acc[2] += xv * w0.z;  acc[3] += xv * w0.w;
    acc[4] += xv * w1v.x; acc[5] += xv * w1v.y; acc[6] += xv * w1v.z; acc[7] += xv * w1v.w;
  }
  #pragma unroll
  for (int off = 32; off; off >>= 1)
    #pragma unroll
    for (int e = 0; e < 8; ++e) acc[e] += __shfl_xor(acc[e], off);

  float mx = acc[0]; int bi = 0;
  #pragma unroll
  for (int e = 1; e < 8; ++e) if (acc[e] > mx) { mx = acc[e]; bi = e; }
  float p[8]; float s = 0.f;
  #pragma unroll
  for (int e = 0; e < 8; ++e) { p[e] = expf(acc[e] - mx); s += p[e]; }
  float inv = 1.f / s;

  __shared__ float pl[4][8];
  if (lane == 0) {
    expert_id[t] = bi;
    gate_val[t] = p[bi] * inv;
    #pragma unroll
    for (int e = 0; e < 8; ++e) pl[wave][e] = p[e] * inv;
  }
  __syncthreads();
  if (threadIdx.x < 8) {
    float m = pl[0][threadIdx.x] + pl[1][threadIdx.x] + pl[2][threadIdx.x] + pl[3][threadIdx.x];
    mepart[blockIdx.x * 8 + threadIdx.x] = m;
  }
}

// ---------------- order-preserving scan (cumsum semantics) ----------------
__global__ __launch_bounds__(1024) void scan_kernel(
    const int* __restrict__ expert_id, const float* __restrict__ gate_val,
    const float* __restrict__ mepart, int nmep,
    int* __restrict__ slot_token, float* __restrict__ slot_gate,
    float* __restrict__ laux_out)
{
  __shared__ int wcnt[16][8];
  __shared__ int base[8];
  __shared__ float red[128][8];
  int tid = threadIdx.x, wave = tid >> 6, lane = tid & 63;
  if (tid < 8) base[tid] = 0;

  int e0 = tid & 7, g = tid >> 3;   // g in 0..127
  float mesum = 0.f;
  for (int r = g; r < nmep; r += 128) mesum += mepart[r * 8 + e0];
  red[g][e0] = mesum;
  __syncthreads();

  for (int tile = 0; tile < T_TOK / 1024; ++tile) {
    int t = tile * 1024 + tid;
    int e = expert_id[t];
    int lp = 0;
    #pragma unroll
    for (int ee = 0; ee < 8; ++ee) {
      unsigned long long m = __ballot(e == ee);
      if (lane == 0) wcnt[wave][ee] = __popcll(m);
      if (ee == e)   lp = __popcll(m & ((1ull << lane) - 1ull));
    }
    __syncthreads();
    int wp = 0;
    for (int w2 = 0; w2 < wave; ++w2) wp += wcnt[w2][e];
    int pos = base[e] + wp + lp;
    if (pos < CAP) {
      slot_token[e * CAP + pos] = t;
      slot_gate[e * CAP + pos] = gate_val[t];
    }
    __syncthreads();
    if (tid < 8) {
      int s = 0;
      for (int w2 = 0; w2 < 16; ++w2) s += wcnt[w2][tid];
      base[tid] += s;
    }
    __syncthreads();
  }

  if (tid < 8) {
    float me = 0.f;
    for (int r = 0; r < 128; ++r) me += red[r][tid];
    me /= (float)T_TOK;
    float ce = (float)base[tid] / (float)T_TOK;
    red[0][tid] = me * ce;
  }
  __syncthreads();
  if (tid == 0) {
    float s = 0.f;
    for (int e = 0; e < 8; ++e) s += red[0][e];
    *laux_out = s * (float)E_NUM;
  }
}

// -------- transpose + f32->bf16 + pack into tiled-swizzled layout --------
__global__ __launch_bounds__(256) void transpose_cvt_kernel(
    const float* __restrict__ in, u16* __restrict__ out, int R, int Cc)
{
  __shared__ float tile[64][65];
  int e = blockIdx.z;
  const float* ine = in + (size_t)e * R * Cc;
  int r0 = blockIdx.y * 64, c0 = blockIdx.x * 64;
  int tr = threadIdx.x >> 4, tc = threadIdx.x & 15;
  #pragma unroll
  for (int it = 0; it < 4; ++it) {
    float4 v = *(const float4*)&ine[(size_t)(r0 + it * 16 + tr) * Cc + c0 + tc * 4];
    tile[it * 16 + tr][tc * 4 + 0] = v.x;
    tile[it * 16 + tr][tc * 4 + 1] = v.y;
    tile[it * 16 + tr][tc * 4 + 2] = v.z;
    tile[it * 16 + tr][tc * 4 + 3] = v.w;
  }
  __syncthreads();
  int nt256 = Cc >> 8, nkt = R >> 6;
  int oc = threadIdx.x >> 2, q = threadIdx.x & 3;
  int n = c0 + oc, k0 = r0 + q * 16;
  u16 vals[16];
  #pragma unroll
  for (int i = 0; i < 16; ++i) vals[i] = f2bf(tile[q * 16 + i][oc]);
  unsigned int w[8];
  #pragma unroll
  for (int i = 0; i < 8; ++i) w[i] = (unsigned int)vals[2 * i] | ((unsigned int)vals[2 * i + 1] << 16);
  uint4 pa; pa.x = w[0]; pa.y = w[1]; pa.z = w[2]; pa.w = w[3];
  uint4 pb; pb.x = w[4]; pb.y = w[5]; pb.z = w[6]; pb.w = w[7];
  *(uint4*)&out[tiled_off(e, n, k0,     nt256, nkt)] = pa;
  *(uint4*)&out[tiled_off(e, n, k0 + 8, nt256, nkt)] = pb;
}

// ------- dispatch: gather tokens -> Xe tiled [E][4][32][2][8192] bf16 -------
__global__ __launch_bounds__(256) void dispatch_kernel(
    const float* __restrict__ x, const int* __restrict__ slot_token,
    u16* __restrict__ Xe)
{
  int slot = blockIdx.x;
  int e = slot >> 10, c = slot & (CAP - 1);
  int t = slot_token[slot];
  int m = threadIdx.x * 8;
  uint4 pk;
  if (t < 0) {
    pk.x = pk.y = pk.z = pk.w = 0u;
  } else {
    const float* xr = x + (size_t)t * M_DIM + m;
    float4 a = *(const float4*)xr;
    float4 b = *(const float4*)(xr + 4);
    pk.x = pack2(a.x, a.y); pk.y = pack2(a.z, a.w);
    pk.z = pack2(b.x, b.y); pk.w = pack2(b.z, b.w);
  }
  *(uint4*)&Xe[tiled_off(e, c, m, CAP >> 8, M_DIM >> 6)] = pk;
}

// ============ 256x256 8-phase MFMA GEMM, asm ds_read fragments ============
// Fragment reads are inline-asm ds_read_b128 (invisible to the compiler's
// alias analysis) so hipcc cannot insert vmcnt(0) drains ordering them
// against outstanding global_load_lds staging. All waits are explicit:
// lgkmcnt(0)+sched_barrier per phase, vmcnt(6) only at phases 4 & 8.
template<int MH, int GATE>
__device__ __forceinline__ void do_phase(
    unsigned aAddr, unsigned bAddr,
    short8 (&bfr)[4], f32x4 (&acc)[8][4],
    const u16* __restrict__ tb, u16* sreg, int skt, int skh,
    int tid, int wave)
{
  short8 af[4];
  unsigned aA = aAddr + MH * 4096;
  if (MH == 0) {
    asm volatile("ds_read_b128 %0, %1 offset:0"    : "=v"(bfr[0]) : "v"(bAddr));
    asm volatile("ds_read_b128 %0, %1 offset:1024" : "=v"(bfr[1]) : "v"(bAddr));
    asm volatile("ds_read_b128 %0, %1 offset:2048" : "=v"(bfr[2]) : "v"(bAddr));
    asm volatile("ds_read_b128 %0, %1 offset:3072" : "=v"(bfr[3]) : "v"(bAddr));
  }
  asm volatile("ds_read_b128 %0, %1 offset:0"    : "=v"(af[0]) : "v"(aA));
  asm volatile("ds_read_b128 %0, %1 offset:1024" : "=v"(af[1]) : "v"(aA));
  asm volatile("ds_read_b128 %0, %1 offset:2048" : "=v"(af[2]) : "v"(aA));
  asm volatile("ds_read_b128 %0, %1 offset:3072" : "=v"(af[3]) : "v"(aA));
  // stage one contiguous 16KB half-tile
  const u16* src = tb + ((size_t)(skt * 2 + skh) << 13);
  #pragma unroll
  for (int j = 0; j < 2; ++j)
    gl_lds16(src + (size_t)(j * 512 + tid) * 8, sreg + (j * 512 + (wave << 6)) * 8);
  __builtin_amdgcn_s_barrier();
  asm volatile("s_waitcnt lgkmcnt(0)");
  __builtin_amdgcn_sched_barrier(0);   // rule 18: keep MFMA below the wait
  __builtin_amdgcn_s_setprio(1);
  #pragma unroll
  for (int m2 = 0; m2 < 4; ++m2)
    #pragma unroll
    for (int n2 = 0; n2 < 4; ++n2)
      acc[MH * 4 + m2][n2] = __builtin_amdgcn_mfma_f32_16x16x32_bf16(
          af[m2], bfr[n2], acc[MH * 4 + m2][n2], 0, 0, 0);
  __builtin_amdgcn_s_setprio(0);
  if (GATE) {
    asm volatile("s_waitcnt vmcnt(6)");
    __builtin_amdgcn_sched_barrier(0);
  }
  __builtin_amdgcn_s_barrier();
}

template<int EPI>
__global__ __launch_bounds__(512, 2) void gemm8_kernel(
    const u16* __restrict__ A,   // tiled [E][CAP/256][K/64][2][8192]
    const u16* __restrict__ B,   // tiled [E][NR/256][K/64][2][8192]
    const float* __restrict__ bias, // [E][NR]
    u16* __restrict__ Hout,      // EPI0: tiled [E][4][F/64][2][8192]
    float* __restrict__ Out,     // EPI1: [T][M]
    const int* __restrict__ slot_token, const float* __restrict__ slot_gate,
    int K, int NR)
{
  __shared__ u16 SA[2][2][8192];  // [buf][k-half][256 rows][32 cols] 64KB
  __shared__ u16 SB[2][2][8192];  // 64KB

  int e = blockIdx.z;
  int n0 = blockIdx.x * 256, m0 = blockIdx.y * 256;
  int nkt = K >> 6;
  const u16* Atb = A + (((size_t)(e * (CAP >> 8) + (m0 >> 8)) * nkt) * 2) * 8192;
  const u16* Btb = B + (((size_t)(e * (NR >> 8) + (n0 >> 8)) * nkt) * 2) * 8192;

  int tid = threadIdx.x, wave = tid >> 6, lane = tid & 63;
  int wr = wave >> 2, wc = wave & 3;
  int l15 = lane & 15, g2 = lane >> 4;

  // ds_read constants: swizzled column-granule offset (u16)
  int rs = (l15 >> 1) & 3;
  int cg = (g2 ^ rs) * 8;
  int arow_base = (wr * 128 + l15) * 32 + cg;
  int brow_base = (wc * 64 + l15) * 32 + cg;

  unsigned aAddr[2][2], bAddr[2][2];
  #pragma unroll
  for (int b = 0; b < 2; ++b)
    #pragma unroll
    for (int h = 0; h < 2; ++h) {
      aAddr[b][h] = lds_off(&SA[b][h][0]) + (unsigned)(arow_base * 2);
      bAddr[b][h] = lds_off(&SB[b][h][0]) + (unsigned)(brow_base * 2);
    }

  f32x4 acc[8][4];
  #pragma unroll
  for (int m = 0; m < 8; ++m)
    #pragma unroll
    for (int n = 0; n < 4; ++n)
      acc[m][n] = (f32x4){0.f, 0.f, 0.f, 0.f};
  short8 bfr[4];

  auto stage0 = [&](const u16* tb, u16* region, int kt, int kh) {
    const u16* src = tb + ((size_t)(kt * 2 + kh) << 13);
    #pragma unroll
    for (int j = 0; j < 2; ++j)
      gl_lds16(src + (size_t)(j * 512 + tid) * 8, region + (j * 512 + (wave << 6)) * 8);
  };

  int nk = K >> 6, ni = nk >> 1;
  // prologue: 7 half-tiles in steady-state issue order; vmcnt(6) proves buf0.
  stage0(Btb, &SB[0][0][0], 0, 0);
  stage0(Atb, &SA[0][0][0], 0, 0);
  stage0(Btb, &SB[0][1][0], 0, 1);
  stage0(Atb, &SA[0][1][0], 0, 1);
  stage0(Btb, &SB[1][0][0], 1, 0);
  stage0(Atb, &SA[1][0][0], 1, 0);
  stage0(Btb, &SB[1][1][0], 1, 1);
  asm volatile("s_waitcnt vmcnt(6)");
  __builtin_amdgcn_sched_barrier(0);
  __builtin_amdgcn_s_barrier();

  #pragma unroll 1
  for (int i = 0; i < ni; ++i) {
    int t1 = 2 * i + 1;                                 // always < nk
    int t2 = 2 * i + 2 < nk ? 2 * i + 2 : nk - 1;       // clamped (staged, not consumed)
    int t3 = 2 * i + 3 < nk ? 2 * i + 3 : nk - 1;
    // P1..P4: compute K-tile 2i (buf0)
    do_phase<0,0>(aAddr[0][0], bAddr[0][0], bfr, acc, Atb, &SA[1][1][0], t1, 1, tid, wave);
    do_phase<1,0>(aAddr[0][0], bAddr[0][0], bfr, acc, Btb, &SB[0][0][0], t2, 0, tid, wave);
    do_phase<0,0>(aAddr[0][1], bAddr[0][1], bfr, acc, Atb, &SA[0][0][0], t2, 0, tid, wave);
    do_phase<1,1>(aAddr[0][1], bAddr[0][1], bfr, acc, Btb, &SB[0][1][0], t2, 1, tid, wave);
    // P5..P8: compute K-tile 2i+1 (buf1)
    do_phase<0,0>(aAddr[1][0], bAddr[1][0], bfr, acc, Atb, &SA[0][1][0], t2, 1, tid, wave);
    do_phase<1,0>(aAddr[1][0], bAddr[1][0], bfr, acc, Btb, &SB[1][0][0], t3, 0, tid, wave);
    do_phase<0,0>(aAddr[1][1], bAddr[1][1], bfr, acc, Atb, &SA[1][0][0], t3, 0, tid, wave);
    do_phase<1,1>(aAddr[1][1], bAddr[1][1], bfr, acc, Btb, &SB[1][1][0], t3, 1, tid, wave);
  }

  int wrb = wr * 128, wcb = wc * 64;
  const float* be = bias + (size_t)e * NR + n0;
  if (EPI == 0) {
    #pragma unroll
    for (int wm = 0; wm < 8; ++wm) {
      #pragma unroll
      for (int j = 0; j < 4; ++j) {
        int r = wrb + wm * 16 + g2 * 4 + j;
        #pragma unroll
        for (int n = 0; n < 4; ++n) {
          int c = wcb + n * 16 + l15;
          float v = acc[wm][n][j] + be[c];
          Hout[tiled_off(e, m0 + r, n0 + c, CAP >> 8, F_DIM >> 6)] = f2bf(gelu_tanh(v));
        }
      }
    }
  } else {
    #pragma unroll
    for (int wm = 0; wm < 8; ++wm) {
      #pragma unroll
      for (int j = 0; j < 4; ++j) {
        int r = wrb + wm * 16 + g2 * 4 + j;
        int slot = e * CAP + m0 + r;
        int tk = slot_token[slot];
        if (tk >= 0) {
          float gv = slot_gate[slot];
          size_t rowoff = (size_t)tk * M_DIM + n0;
          #pragma unroll
          for (int n = 0; n < 4; ++n) {
            int c = wcb + n * 16 + l15;
            Out[rowoff + c] = gv * (acc[wm][n][j] + be[c]);
          }
        }
      }
    }
  }
}

extern "C" void kernel_launch(void* const* d_in, const int* in_sizes, int n_in,
                              void* d_out, int out_size, void* d_ws, size_t ws_size,
                              hipStream_t stream) {
  const float* x  = (const float*)d_in[0];
  const float* wg = (const float*)d_in[1];
  const float* w1 = (const float*)d_in[2];
  const float* b1 = (const float*)d_in[3];
  const float* w2 = (const float*)d_in[4];
  const float* b2 = (const float*)d_in[5];
  float* out = (float*)d_out;

  char* ws = (char*)d_ws;
  size_t o = 0;
  auto alloc = [&](size_t bytes) -> void* {
    void* p = ws + o;
    o += (bytes + 255) & ~(size_t)255;
    return p;
  };
  u16*   w1T        = (u16*)  alloc((size_t)E_NUM * F_DIM * M_DIM * 2);  // 256 MB
  u16*   w2T        = (u16*)  alloc((size_t)E_NUM * M_DIM * F_DIM * 2);  // 256 MB
  u16*   h          = (u16*)  alloc((size_t)E_NUM * CAP * F_DIM * 2);    // 128 MB
  u16*   Xe         = (u16*)  alloc((size_t)E_NUM * CAP * M_DIM * 2);    // 32 MB
  int*   expert_id  = (int*)  alloc(T_TOK * 4);
  float* gate_val   = (float*)alloc(T_TOK * 4);
  int*   slot_token = (int*)  alloc(E_NUM * CAP * 4);
  float* slot_gate  = (float*)alloc(E_NUM * CAP * 4);
  float* mepart     = (float*)alloc(2048 * 8 * 4);

  hipMemsetAsync(d_out, 0, (size_t)out_size * 4, stream);
  hipMemsetAsync(slot_token, 0xFF, E_NUM * CAP * 4, stream);

  // L3-warmth ordering: each GEMM's weight matrix is the LAST large stream
  // written before that GEMM reads it.
  gating_kernel<<<T_TOK / 4, 256, 0, stream>>>(x, wg, expert_id, gate_val, mepart);
  scan_kernel<<<1, 1024, 0, stream>>>(expert_id, gate_val, mepart, 2048,
                                      slot_token, slot_gate, out + (out_size - 1));
  dispatch_kernel<<<E_NUM * CAP, 256, 0, stream>>>(x, slot_token, Xe);
  transpose_cvt_kernel<<<dim3(128, 32, 8), 256, 0, stream>>>(w1, w1T, 2048, 8192);
  gemm8_kernel<0><<<dim3(F_DIM / 256, CAP / 256, E_NUM), 512, 0, stream>>>(
      Xe, w1T, b1, h, nullptr, nullptr, nullptr, M_DIM, F_DIM);
  transpose_cvt_kernel<<<dim3(32, 128, 8), 256, 0, stream>>>(w2, w2T, 8192, 2048);
  gemm8_kernel<1><<<dim3(M_DIM / 256, CAP / 256, E_NUM), 512, 0, stream>>>(
      h, w2T, b2, nullptr, out, slot_token, slot_gate, F_DIM, M_DIM);
}